// Round 1
// baseline (150.941 us; speedup 1.0000x reference)
//
#include <hip/hip_runtime.h>
#include <hip/hip_bf16.h>

// DeConv2d = 32 independent per-channel MLPs (128->256->256->4) over 8192 pixels,
// then 2x2 pixel shuffle. Compute-bound -> bf16 MFMA (threshold 1.05e-2 permits).
//
// Workspace layout (d_ws):
//   pix  [8192][128] bf16   @ 0        (2 MB)   x transposed to pixel-major
//   W1t  [32][256][128] bf16 @ 2 MB    (2 MB)   W1 transposed to [o][n][k]
//   W2t  [32][256][256] bf16 @ 4 MB    (4 MB)
//   W3t  [32][16][256]  bf16 @ 8 MB    (256 KB) rows 4..15 zero-padded

#define IC    128
#define IHW   1024
#define OCH   32
#define HDIM  256
#define BM    64

typedef float  f32x4  __attribute__((ext_vector_type(4)));
typedef __bf16 bf16x8 __attribute__((ext_vector_type(8)));

static __device__ __forceinline__ unsigned short f2bf(float f) {
  __hip_bfloat16 h = __float2bfloat16(f);
  return __builtin_bit_cast(unsigned short, h);
}

// ---- conversion / transpose pre-passes (memory-bound, ~10us total) ----

__global__ void conv_pix_k(const float* __restrict__ x, unsigned short* __restrict__ pix) {
  int idx = blockIdx.x * 256 + threadIdx.x;          // 8*1024*128 = 1,048,576
  int c = idx & 127;
  int rest = idx >> 7;                               // n*1024 + p
  int n = rest >> 10, p = rest & 1023;
  pix[idx] = f2bf(x[(n * IC + c) * IHW + p]);
}

__global__ void conv_w1_k(const float* __restrict__ W1, unsigned short* __restrict__ W1t) {
  int idx = blockIdx.x * 256 + threadIdx.x;          // 32*256*128 = 1,048,576
  int k = idx & 127;
  int nn = (idx >> 7) & 255;
  int o = idx >> 15;
  W1t[idx] = f2bf(W1[(o * IC + k) * HDIM + nn]);
}

__global__ void conv_w2_k(const float* __restrict__ W2, unsigned short* __restrict__ W2t) {
  int idx = blockIdx.x * 256 + threadIdx.x;          // 32*256*256 = 2,097,152
  int k = idx & 255;
  int nn = (idx >> 8) & 255;
  int o = idx >> 16;
  W2t[idx] = f2bf(W2[(o * HDIM + k) * HDIM + nn]);
}

__global__ void conv_w3_k(const float* __restrict__ W3, unsigned short* __restrict__ W3t) {
  int idx = blockIdx.x * 256 + threadIdx.x;          // 32*16*256 = 131,072
  int k = idx & 255;
  int nn = (idx >> 8) & 15;
  int o = idx >> 12;
  W3t[idx] = (nn < 4) ? f2bf(W3[(o * HDIM + k) * 4 + nn]) : (unsigned short)0;
}

// ---- fused 3-layer MLP, one block = (group o, 64-pixel tile) ----
// MFMA operands swapped: A = weight rows (n), B = pixel cols (m), so D frag has
// col=lane&15 -> pixel m, row=(lane>>4)*4+reg -> n (4 contiguous n per lane -> 8B LDS stores).
// LDS: [0,16K) pix tile (then reused for h2 [0,32K)), [32K,64K) h1. All XOR-swizzled
// with byte ^= ((m&7)<<4) to kill the 256/512B-stride bank conflicts (G4).

__global__ __launch_bounds__(256, 2) void fused_mlp_k(
    const unsigned short* __restrict__ pix,
    const unsigned short* __restrict__ W1t,
    const unsigned short* __restrict__ W2t,
    const unsigned short* __restrict__ W3t,
    const float* __restrict__ b1,
    const float* __restrict__ b2,
    const float* __restrict__ b3f,
    float* __restrict__ out)
{
  __shared__ __align__(16) char lds[65536];
  const int t    = threadIdx.x;
  const int lane = t & 63;
  const int w    = t >> 6;          // wave 0..3
  const int bx   = blockIdx.x;
  const int o    = bx >> 7;         // 128 m-tiles per group
  const int m0   = (bx & 127) * BM;

  const int l15  = lane & 15;
  const int lg   = lane >> 4;       // 0..3
  const int kgrp = lg << 3;         // lane's k sub-offset (0,8,16,24)

  // ---- stage pix tile [64][128] bf16 -> LDS[0..16K), swizzled
#pragma unroll
  for (int r = 0; r < 4; ++r) {
    int chunk = r * 256 + t;                 // coalesced 16B chunks
    int m = chunk >> 4;
    int c16 = chunk & 15;
    uint4 v = *reinterpret_cast<const uint4*>(pix + (m0 + m) * IC + c16 * 8);
    int off = ((m << 8) + (c16 << 4)) ^ ((m & 7) << 4);
    *reinterpret_cast<uint4*>(lds + off) = v;
  }
  __syncthreads();

  const f32x4 vzero = {0.f, 0.f, 0.f, 0.f};
  const int nbase = (w << 6) + l15;          // A-frag row base (this wave's n-slice)

  // ================= layer 1: h1 = relu(pix @ W1 + b1), K=128 =================
  f32x4 acc[4][4];
#pragma unroll
  for (int ni = 0; ni < 4; ++ni)
#pragma unroll
    for (int mi = 0; mi < 4; ++mi) acc[ni][mi] = vzero;

  const unsigned short* W1o = W1t + (o << 15);
#pragma unroll
  for (int ks = 0; ks < 4; ++ks) {
    bf16x8 aw[4], bp[4];
#pragma unroll
    for (int nf = 0; nf < 4; ++nf)
      aw[nf] = __builtin_bit_cast(bf16x8,
          *reinterpret_cast<const uint4*>(W1o + (nbase + (nf << 4)) * IC + (ks << 5) + kgrp));
#pragma unroll
    for (int mf = 0; mf < 4; ++mf) {
      int m = (mf << 4) + l15;
      int off = ((m << 8) + (ks << 6) + (kgrp << 1)) ^ ((m & 7) << 4);
      bp[mf] = *reinterpret_cast<const bf16x8*>(lds + off);
    }
#pragma unroll
    for (int nf = 0; nf < 4; ++nf)
#pragma unroll
      for (int mf = 0; mf < 4; ++mf)
        acc[nf][mf] = __builtin_amdgcn_mfma_f32_16x16x32_bf16(aw[nf], bp[mf], acc[nf][mf], 0, 0, 0);
  }

  // epilogue: bias+relu, pack 4 contiguous n as bf16x4 -> h1 @ LDS[32K..64K)
  {
    const float* b1o = b1 + (o << 8);
#pragma unroll
    for (int nf = 0; nf < 4; ++nf) {
      int n0 = (w << 6) + (nf << 4) + (lg << 2);
      float bb0 = b1o[n0], bb1 = b1o[n0 + 1], bb2 = b1o[n0 + 2], bb3 = b1o[n0 + 3];
#pragma unroll
      for (int mf = 0; mf < 4; ++mf) {
        int m = (mf << 4) + l15;
        ushort4 hv;
        hv.x = f2bf(fmaxf(acc[nf][mf][0] + bb0, 0.f));
        hv.y = f2bf(fmaxf(acc[nf][mf][1] + bb1, 0.f));
        hv.z = f2bf(fmaxf(acc[nf][mf][2] + bb2, 0.f));
        hv.w = f2bf(fmaxf(acc[nf][mf][3] + bb3, 0.f));
        int off = 32768 + (((m << 9) + (n0 << 1)) ^ ((m & 7) << 4));
        *reinterpret_cast<ushort4*>(lds + off) = hv;
      }
    }
  }
  __syncthreads();

  // ================= layer 2: h2 = relu(h1 @ W2 + b2), K=256 =================
#pragma unroll
  for (int ni = 0; ni < 4; ++ni)
#pragma unroll
    for (int mi = 0; mi < 4; ++mi) acc[ni][mi] = vzero;

  const unsigned short* W2o = W2t + (o << 16);
#pragma unroll
  for (int ks = 0; ks < 8; ++ks) {
    bf16x8 aw[4], bp[4];
#pragma unroll
    for (int nf = 0; nf < 4; ++nf)
      aw[nf] = __builtin_bit_cast(bf16x8,
          *reinterpret_cast<const uint4*>(W2o + (nbase + (nf << 4)) * HDIM + (ks << 5) + kgrp));
#pragma unroll
    for (int mf = 0; mf < 4; ++mf) {
      int m = (mf << 4) + l15;
      int off = 32768 + (((m << 9) + (ks << 6) + (kgrp << 1)) ^ ((m & 7) << 4));
      bp[mf] = *reinterpret_cast<const bf16x8*>(lds + off);
    }
#pragma unroll
    for (int nf = 0; nf < 4; ++nf)
#pragma unroll
      for (int mf = 0; mf < 4; ++mf)
        acc[nf][mf] = __builtin_amdgcn_mfma_f32_16x16x32_bf16(aw[nf], bp[mf], acc[nf][mf], 0, 0, 0);
  }

  // epilogue -> h2 @ LDS[0..32K) (pix region is dead; barrier above covers reuse)
  {
    const float* b2o = b2 + (o << 8);
#pragma unroll
    for (int nf = 0; nf < 4; ++nf) {
      int n0 = (w << 6) + (nf << 4) + (lg << 2);
      float bb0 = b2o[n0], bb1 = b2o[n0 + 1], bb2 = b2o[n0 + 2], bb3 = b2o[n0 + 3];
#pragma unroll
      for (int mf = 0; mf < 4; ++mf) {
        int m = (mf << 4) + l15;
        ushort4 hv;
        hv.x = f2bf(fmaxf(acc[nf][mf][0] + bb0, 0.f));
        hv.y = f2bf(fmaxf(acc[nf][mf][1] + bb1, 0.f));
        hv.z = f2bf(fmaxf(acc[nf][mf][2] + bb2, 0.f));
        hv.w = f2bf(fmaxf(acc[nf][mf][3] + bb3, 0.f));
        int off = ((m << 9) + (n0 << 1)) ^ ((m & 7) << 4);
        *reinterpret_cast<ushort4*>(lds + off) = hv;
      }
    }
  }
  __syncthreads();

  // ================= layer 3: out = h2 @ W3 + b3, K=256, N=4 =================
  // wave w owns pixels m3 = w*16 + (lane&15); W3t rows 4..15 are zero padding.
  f32x4 acc3 = vzero;
  const unsigned short* W3o = W3t + (o << 12);
  const int m3 = (w << 4) + l15;
#pragma unroll
  for (int ks = 0; ks < 8; ++ks) {
    bf16x8 a3 = __builtin_bit_cast(bf16x8,
        *reinterpret_cast<const uint4*>(W3o + l15 * HDIM + (ks << 5) + kgrp));
    int off = ((m3 << 9) + (ks << 6) + (kgrp << 1)) ^ ((m3 & 7) << 4);
    bf16x8 bh = *reinterpret_cast<const bf16x8*>(lds + off);
    acc3 = __builtin_amdgcn_mfma_f32_16x16x32_bf16(a3, bh, acc3, 0, 0, 0);
  }

  // D rows 0..3 (= kk) live in lanes 0..15; pixel-shuffle scatter to out
  if (lane < 16) {
    int pixel = m0 + m3;
    int n = pixel >> 10;
    int p = pixel & 1023;
    int ii = p >> 5, jj = p & 31;
    float* ob = out + (((n * OCH + o) << 12));
#pragma unroll
    for (int j = 0; j < 4; ++j) {
      int kh = j >> 1, kw = j & 1;
      ob[((ii << 1) + kh) * 64 + (jj << 1) + kw] = acc3[j] + b3f[(o << 2) + j];
    }
  }
}

extern "C" void kernel_launch(void* const* d_in, const int* in_sizes, int n_in,
                              void* d_out, int out_size, void* d_ws, size_t ws_size,
                              hipStream_t stream) {
  const float* x  = (const float*)d_in[0];
  const float* W1 = (const float*)d_in[1];
  const float* b1 = (const float*)d_in[2];
  const float* W2 = (const float*)d_in[3];
  const float* b2 = (const float*)d_in[4];
  const float* W3 = (const float*)d_in[5];
  const float* b3 = (const float*)d_in[6];
  float* out = (float*)d_out;

  char* ws = (char*)d_ws;
  unsigned short* pix = (unsigned short*)(ws);
  unsigned short* W1t = (unsigned short*)(ws + (size_t)(2u << 20));
  unsigned short* W2t = (unsigned short*)(ws + (size_t)(4u << 20));
  unsigned short* W3t = (unsigned short*)(ws + (size_t)(8u << 20));

  conv_pix_k<<<4096, 256, 0, stream>>>(x, pix);
  conv_w1_k <<<4096, 256, 0, stream>>>(W1, W1t);
  conv_w2_k <<<8192, 256, 0, stream>>>(W2, W2t);
  conv_w3_k <<<512,  256, 0, stream>>>(W3, W3t);
  fused_mlp_k<<<4096, 256, 0, stream>>>(pix, W1t, W2t, W3t, b1, b2, b3, out);
}

// Round 3
// 144.307 us; speedup vs baseline: 1.0460x; 1.0460x over previous
//
#include <hip/hip_runtime.h>
#include <hip/hip_bf16.h>

// DeConv2d = 32 independent per-channel MLPs (128->256->256->4) over 8192 pixels,
// then 2x2 pixel shuffle. Compute-bound -> bf16 MFMA.
//
// R2 changes vs R1 (latency-bound at 22% occupancy):
//  - LDS 64KB -> 48KB (h2 overwrites h1 after a barrier) => 3 blocks/CU
//  - explicit 1-deep weight-fragment prefetch in all K-loops
//  - XCD-clustered group mapping: 4 groups (~800KB weights) per XCD L2
// (R3 = R2 resubmitted: container died before the R2 bench ran.)
//
// Workspace: pix [8192][128] bf16 @0; W1t [32][256][128] @2MB; W2t [32][256][256] @4MB;
//            W3t [32][16][256] @8MB (rows 4..15 zero).

#define IC    128
#define IHW   1024
#define OCH   32
#define HDIM  256
#define BM    64

typedef float  f32x4  __attribute__((ext_vector_type(4)));
typedef __bf16 bf16x8 __attribute__((ext_vector_type(8)));

static __device__ __forceinline__ unsigned short f2bf(float f) {
  __hip_bfloat16 h = __float2bfloat16(f);
  return __builtin_bit_cast(unsigned short, h);
}

static __device__ __forceinline__ bf16x8 ld16(const unsigned short* p) {
  return __builtin_bit_cast(bf16x8, *reinterpret_cast<const uint4*>(p));
}

// ---- conversion / transpose pre-passes ----

__global__ void conv_pix_k(const float* __restrict__ x, unsigned short* __restrict__ pix) {
  int idx = blockIdx.x * 256 + threadIdx.x;
  int c = idx & 127;
  int rest = idx >> 7;
  int n = rest >> 10, p = rest & 1023;
  pix[idx] = f2bf(x[(n * IC + c) * IHW + p]);
}

__global__ void conv_w1_k(const float* __restrict__ W1, unsigned short* __restrict__ W1t) {
  int idx = blockIdx.x * 256 + threadIdx.x;
  int k = idx & 127;
  int nn = (idx >> 7) & 255;
  int o = idx >> 15;
  W1t[idx] = f2bf(W1[(o * IC + k) * HDIM + nn]);
}

__global__ void conv_w2_k(const float* __restrict__ W2, unsigned short* __restrict__ W2t) {
  int idx = blockIdx.x * 256 + threadIdx.x;
  int k = idx & 255;
  int nn = (idx >> 8) & 255;
  int o = idx >> 16;
  W2t[idx] = f2bf(W2[(o * HDIM + k) * HDIM + nn]);
}

__global__ void conv_w3_k(const float* __restrict__ W3, unsigned short* __restrict__ W3t) {
  int idx = blockIdx.x * 256 + threadIdx.x;
  int k = idx & 255;
  int nn = (idx >> 8) & 15;
  int o = idx >> 12;
  W3t[idx] = (nn < 4) ? f2bf(W3[(o * HDIM + k) * 4 + nn]) : (unsigned short)0;
}

// ---- fused 3-layer MLP ----
// Block = (group o, 64-pixel tile). A = weight rows (n), B = pixel cols (m):
// D frag col=lane&15 -> pixel m, row=(lane>>4)*4+reg -> n (4 contiguous n / lane).
// LDS: [0,16K) pix tile; [16K,48K) h1 then (after barrier) h2. XOR swizzle ^((m&7)<<4).

__global__ __launch_bounds__(256, 3) void fused_mlp_k(
    const unsigned short* __restrict__ pix,
    const unsigned short* __restrict__ W1t,
    const unsigned short* __restrict__ W2t,
    const unsigned short* __restrict__ W3t,
    const float* __restrict__ b1,
    const float* __restrict__ b2,
    const float* __restrict__ b3f,
    float* __restrict__ out)
{
  __shared__ __align__(16) char lds[49152];
  const int t    = threadIdx.x;
  const int lane = t & 63;
  const int w    = t >> 6;
  const int bx   = blockIdx.x;
  const int o    = ((bx & 7) << 2) | ((bx >> 3) & 3);   // 4 groups per XCD
  const int m0   = (bx >> 5) * BM;

  const int l15  = lane & 15;
  const int lg   = lane >> 4;
  const int kgrp = lg << 3;

  // ---- stage pix tile [64][128] bf16 -> LDS[0..16K), swizzled
#pragma unroll
  for (int r = 0; r < 4; ++r) {
    int chunk = r * 256 + t;
    int m = chunk >> 4;
    int c16 = chunk & 15;
    uint4 v = *reinterpret_cast<const uint4*>(pix + (m0 + m) * IC + c16 * 8);
    int off = ((m << 8) + (c16 << 4)) ^ ((m & 7) << 4);
    *reinterpret_cast<uint4*>(lds + off) = v;
  }
  __syncthreads();

  const f32x4 vzero = {0.f, 0.f, 0.f, 0.f};
  const int nbase = (w << 6) + l15;

  f32x4 acc[4][4];
  bf16x8 awc[4], awn[4], bp[4];

  // ================= layer 1: K=128 =================
#pragma unroll
  for (int ni = 0; ni < 4; ++ni)
#pragma unroll
    for (int mi = 0; mi < 4; ++mi) acc[ni][mi] = vzero;

  const unsigned short* W1p = W1t + (o << 15) + nbase * IC + kgrp;
#pragma unroll
  for (int nf = 0; nf < 4; ++nf) awc[nf] = ld16(W1p + (nf << 4) * IC);

#pragma unroll
  for (int ks = 0; ks < 4; ++ks) {
    if (ks < 3) {
#pragma unroll
      for (int nf = 0; nf < 4; ++nf)
        awn[nf] = ld16(W1p + (nf << 4) * IC + ((ks + 1) << 5));
    }
#pragma unroll
    for (int mf = 0; mf < 4; ++mf) {
      int m = (mf << 4) + l15;
      int off = ((m << 8) + (ks << 6) + (kgrp << 1)) ^ ((m & 7) << 4);
      bp[mf] = *reinterpret_cast<const bf16x8*>(lds + off);
    }
#pragma unroll
    for (int nf = 0; nf < 4; ++nf)
#pragma unroll
      for (int mf = 0; mf < 4; ++mf)
        acc[nf][mf] = __builtin_amdgcn_mfma_f32_16x16x32_bf16(awc[nf], bp[mf], acc[nf][mf], 0, 0, 0);
#pragma unroll
    for (int nf = 0; nf < 4; ++nf) awc[nf] = awn[nf];
  }

  // epilogue: bias+relu -> h1 @ LDS[16K..48K)
  {
    const float* b1o = b1 + (o << 8);
#pragma unroll
    for (int nf = 0; nf < 4; ++nf) {
      int n0 = (w << 6) + (nf << 4) + (lg << 2);
      f32x4 bb = *reinterpret_cast<const f32x4*>(b1o + n0);
#pragma unroll
      for (int mf = 0; mf < 4; ++mf) {
        int m = (mf << 4) + l15;
        ushort4 hv;
        hv.x = f2bf(fmaxf(acc[nf][mf][0] + bb[0], 0.f));
        hv.y = f2bf(fmaxf(acc[nf][mf][1] + bb[1], 0.f));
        hv.z = f2bf(fmaxf(acc[nf][mf][2] + bb[2], 0.f));
        hv.w = f2bf(fmaxf(acc[nf][mf][3] + bb[3], 0.f));
        int off = 16384 + (((m << 9) + (n0 << 1)) ^ ((m & 7) << 4));
        *reinterpret_cast<ushort4*>(lds + off) = hv;
      }
    }
  }
  __syncthreads();

  // ================= layer 2: K=256 =================
#pragma unroll
  for (int ni = 0; ni < 4; ++ni)
#pragma unroll
    for (int mi = 0; mi < 4; ++mi) acc[ni][mi] = vzero;

  const unsigned short* W2p = W2t + (o << 16) + nbase * HDIM + kgrp;
#pragma unroll
  for (int nf = 0; nf < 4; ++nf) awc[nf] = ld16(W2p + (nf << 4) * HDIM);

#pragma unroll
  for (int ks = 0; ks < 8; ++ks) {
    if (ks < 7) {
#pragma unroll
      for (int nf = 0; nf < 4; ++nf)
        awn[nf] = ld16(W2p + (nf << 4) * HDIM + ((ks + 1) << 5));
    }
#pragma unroll
    for (int mf = 0; mf < 4; ++mf) {
      int m = (mf << 4) + l15;
      int off = 16384 + (((m << 9) + (ks << 6) + (kgrp << 1)) ^ ((m & 7) << 4));
      bp[mf] = *reinterpret_cast<const bf16x8*>(lds + off);
    }
#pragma unroll
    for (int nf = 0; nf < 4; ++nf)
#pragma unroll
      for (int mf = 0; mf < 4; ++mf)
        acc[nf][mf] = __builtin_amdgcn_mfma_f32_16x16x32_bf16(awc[nf], bp[mf], acc[nf][mf], 0, 0, 0);
#pragma unroll
    for (int nf = 0; nf < 4; ++nf) awc[nf] = awn[nf];
  }

  __syncthreads();   // all h1 reads done before h2 overwrites the region

  // epilogue -> h2 over h1's region
  {
    const float* b2o = b2 + (o << 8);
#pragma unroll
    for (int nf = 0; nf < 4; ++nf) {
      int n0 = (w << 6) + (nf << 4) + (lg << 2);
      f32x4 bb = *reinterpret_cast<const f32x4*>(b2o + n0);
#pragma unroll
      for (int mf = 0; mf < 4; ++mf) {
        int m = (mf << 4) + l15;
        ushort4 hv;
        hv.x = f2bf(fmaxf(acc[nf][mf][0] + bb[0], 0.f));
        hv.y = f2bf(fmaxf(acc[nf][mf][1] + bb[1], 0.f));
        hv.z = f2bf(fmaxf(acc[nf][mf][2] + bb[2], 0.f));
        hv.w = f2bf(fmaxf(acc[nf][mf][3] + bb[3], 0.f));
        int off = 16384 + (((m << 9) + (n0 << 1)) ^ ((m & 7) << 4));
        *reinterpret_cast<ushort4*>(lds + off) = hv;
      }
    }
  }
  __syncthreads();

  // ================= layer 3: K=256, N=4 (W3t zero-padded to 16) =================
  f32x4 acc3 = vzero;
  const unsigned short* W3p = W3t + (o << 12) + l15 * HDIM + kgrp;
  const int m3 = (w << 4) + l15;
  bf16x8 a3c = ld16(W3p), a3n;
#pragma unroll
  for (int ks = 0; ks < 8; ++ks) {
    if (ks < 7) a3n = ld16(W3p + ((ks + 1) << 5));
    int off = 16384 + (((m3 << 9) + (ks << 6) + (kgrp << 1)) ^ ((m3 & 7) << 4));
    bf16x8 bh = *reinterpret_cast<const bf16x8*>(lds + off);
    acc3 = __builtin_amdgcn_mfma_f32_16x16x32_bf16(a3c, bh, acc3, 0, 0, 0);
    a3c = a3n;
  }

  if (lane < 16) {
    int pixel = m0 + m3;
    int n = pixel >> 10;
    int p = pixel & 1023;
    int ii = p >> 5, jj = p & 31;
    float* ob = out + (((n * OCH + o) << 12));
#pragma unroll
    for (int j = 0; j < 4; ++j) {
      int kh = j >> 1, kw = j & 1;
      ob[((ii << 1) + kh) * 64 + (jj << 1) + kw] = acc3[j] + b3f[(o << 2) + j];
    }
  }
}

extern "C" void kernel_launch(void* const* d_in, const int* in_sizes, int n_in,
                              void* d_out, int out_size, void* d_ws, size_t ws_size,
                              hipStream_t stream) {
  const float* x  = (const float*)d_in[0];
  const float* W1 = (const float*)d_in[1];
  const float* b1 = (const float*)d_in[2];
  const float* W2 = (const float*)d_in[3];
  const float* b2 = (const float*)d_in[4];
  const float* W3 = (const float*)d_in[5];
  const float* b3 = (const float*)d_in[6];
  float* out = (float*)d_out;

  char* ws = (char*)d_ws;
  unsigned short* pix = (unsigned short*)(ws);
  unsigned short* W1t = (unsigned short*)(ws + (size_t)(2u << 20));
  unsigned short* W2t = (unsigned short*)(ws + (size_t)(4u << 20));
  unsigned short* W3t = (unsigned short*)(ws + (size_t)(8u << 20));

  conv_pix_k<<<4096, 256, 0, stream>>>(x, pix);
  conv_w1_k <<<4096, 256, 0, stream>>>(W1, W1t);
  conv_w2_k <<<8192, 256, 0, stream>>>(W2, W2t);
  conv_w3_k <<<512,  256, 0, stream>>>(W3, W3t);
  fused_mlp_k<<<4096, 256, 0, stream>>>(pix, W1t, W2t, W3t, b1, b2, b3, out);
}

// Round 4
// 110.641 us; speedup vs baseline: 1.3642x; 1.3043x over previous
//
#include <hip/hip_runtime.h>
#include <hip/hip_bf16.h>

// DeConv2d = 32 independent per-channel MLPs (128->256->256->4) over 8192 pixels,
// then 2x2 pixel shuffle. Compute-bound -> bf16 MFMA.
//
// R4: R3 was latency-bound (MfmaUtil 17% = exactly the MFMA-pipe floor smeared
// over 5x the time; in-loop global weight loads were the stall). Changes:
//  - weights fully RESIDENT in VGPRs per wave (8-wave block, 32-n-slice/wave),
//    loaded once per block, reused across 4 pixel-tiles (256 px/block)
//  - pix tiles double-buffered via global_load_lds(16B) w/ pre-swizzled source
//  - inner loops: ds_read (1-ks-ahead pipelined) + MFMA only
//  - layer-3 K-split across 8 waves, partials combined via LDS
//  - prepasses: LDS-tiled coalesced transpose (R3's were fully uncoalesced)
//
// Workspace: pix [8192][128] bf16 @0; W1t [32][256][128] @2MB; W2t [32][256][256] @4MB;
//            W3t [32][16][256] @8MB (rows 4..15 zero).

#define IC    128
#define IHW   1024
#define OCH   32
#define HDIM  256

typedef float  f32x4  __attribute__((ext_vector_type(4)));
typedef float  f32x2  __attribute__((ext_vector_type(2)));
typedef __bf16 bf16x8 __attribute__((ext_vector_type(8)));
typedef unsigned short us8 __attribute__((ext_vector_type(8)));
typedef unsigned int u32;

static __device__ __forceinline__ unsigned short f2bf(float f) {
  __hip_bfloat16 h = __float2bfloat16(f);
  return __builtin_bit_cast(unsigned short, h);
}

static __device__ __forceinline__ bf16x8 ld16(const unsigned short* p) {
  return __builtin_bit_cast(bf16x8, *reinterpret_cast<const uint4*>(p));
}

// async global->LDS, 16B per lane; LDS dest = uniform base + lane*16
static __device__ __forceinline__ void gl_lds16(const unsigned short* g, char* l) {
  __builtin_amdgcn_global_load_lds(
      (const __attribute__((address_space(1))) u32*)g,
      (__attribute__((address_space(3))) u32*)l,
      16, 0, 0);
}

// ---- coalesced transpose prepass: dst[b][c][r] (bf16) = src[b][r][c] (f32) ----
// NR, NC multiples of 64. grid = batch * (NR/64) * (NC/64), block 256.
__global__ __launch_bounds__(256) void transpose_bf16_k(
    const float* __restrict__ src, unsigned short* __restrict__ dst,
    int NR, int NC, int nrt, int nct)
{
  __shared__ float tl[64 * 65];
  const int bid = blockIdx.x;
  const int ct = bid % nct;
  const int rt = (bid / nct) % nrt;
  const int b  = bid / (nct * nrt);
  const int t  = threadIdx.x;

  const float* sb = src + ((size_t)b * NR + (rt << 6)) * NC + (ct << 6);
  const int col = (t & 15) << 2;
  const int rq  = t >> 4;
#pragma unroll
  for (int rr = 0; rr < 4; ++rr) {
    int row = (rr << 4) + rq;
    f32x4 v = *reinterpret_cast<const f32x4*>(sb + row * NC + col);
#pragma unroll
    for (int i = 0; i < 4; ++i) tl[row * 65 + col + i] = v[i];
  }
  __syncthreads();

  unsigned short* db = dst + ((size_t)b * NC + (ct << 6)) * NR + (rt << 6);
  const int r0 = (t & 7) << 3;
  const int cq = t >> 3;
#pragma unroll
  for (int cr = 0; cr < 2; ++cr) {
    int c = (cr << 5) + cq;
    us8 vv;
#pragma unroll
    for (int i = 0; i < 8; ++i) vv[i] = f2bf(tl[(r0 + i) * 65 + c]);
    *reinterpret_cast<us8*>(db + (size_t)c * NR + r0) = vv;
  }
}

// W3 is tiny (128K elems): simple kernel, rows 4..15 zero-padded
__global__ void conv_w3_k(const float* __restrict__ W3, unsigned short* __restrict__ W3t) {
  int idx = blockIdx.x * 256 + threadIdx.x;   // 32*16*256
  int k = idx & 255;
  int nn = (idx >> 8) & 15;
  int o = idx >> 12;
  W3t[idx] = (nn < 4) ? f2bf(W3[(o * HDIM + k) * 4 + nn]) : (unsigned short)0;
}

// ---- fused 3-layer MLP ----
// Block = 512 threads = 8 waves, (group o, 256 pixels as 4 tiles of 64).
// Wave w owns n-rows [w*32, w*32+32) for layers 1-2 (A-operand = weights).
// D frag: col=lane&15 -> pixel m, row=(lane>>4)*4+reg -> n.
// LDS: pix dbuf 2x16KB @0; h (h1 then h2) 32KB @32768. Swizzle ^((m&7)<<4).
__global__ __launch_bounds__(512, 2) void fused_mlp_k(
    const unsigned short* __restrict__ pix,
    const unsigned short* __restrict__ W1t,
    const unsigned short* __restrict__ W2t,
    const unsigned short* __restrict__ W3t,
    const float* __restrict__ b1,
    const float* __restrict__ b2,
    const float* __restrict__ b3f,
    float* __restrict__ out)
{
  __shared__ __align__(16) char lds[65536];
  const int t    = threadIdx.x;
  const int lane = t & 63;
  const int w    = t >> 6;                         // 0..7
  const int bx   = blockIdx.x;
  const int o    = ((bx & 7) << 2) | ((bx >> 3) & 3);   // 4 groups per XCD
  const int mblk = bx >> 5;                        // 0..31
  const int pixbase = mblk << 8;                   // 256 px per block

  const int l15  = lane & 15;
  const int lg   = lane >> 4;
  const int kgrp = lg << 3;

  // ---- resident weight fragments (loaded once, reused over 4 tiles) ----
  bf16x8 W1r[2][4], W2r[2][8], W3r[4];
  {
    const unsigned short* p1 = W1t + (o << 15) + ((w << 5) + l15) * IC + kgrp;
#pragma unroll
    for (int nf = 0; nf < 2; ++nf)
#pragma unroll
      for (int ks = 0; ks < 4; ++ks)
        W1r[nf][ks] = ld16(p1 + (nf << 4) * IC + (ks << 5));
    const unsigned short* p2 = W2t + (o << 16) + ((w << 5) + l15) * HDIM + kgrp;
#pragma unroll
    for (int nf = 0; nf < 2; ++nf)
#pragma unroll
      for (int ks = 0; ks < 8; ++ks)
        W2r[nf][ks] = ld16(p2 + (nf << 4) * HDIM + (ks << 5));
    // layer-3 K-split: wave w covers k-half (w>>2), pixels quarter (w&3)
    const unsigned short* p3 = W3t + (o << 12) + l15 * HDIM + ((w >> 2) << 7) + kgrp;
#pragma unroll
    for (int i = 0; i < 4; ++i)
      W3r[i] = ld16(p3 + (i << 5));
  }

  // ---- stage pix tile 0 into buf0 (pre-swizzled source, linear LDS dest) ----
#pragma unroll
  for (int c = 0; c < 2; ++c) {
    int slot = (w << 7) + (c << 6) + lane;
    int m = slot >> 4, j = slot & 15;
    gl_lds16(pix + (size_t)(pixbase + m) * IC + ((j ^ (m & 7)) << 3),
             lds + ((w << 7) + (c << 6)) * 16);
  }
  __syncthreads();

  const f32x4 vzero = {0.f, 0.f, 0.f, 0.f};
  const float* b1o = b1 + (o << 8);
  const float* b2o = b2 + (o << 8);

  for (int tt = 0; tt < 4; ++tt) {
    const int cur = tt & 1;
    char* pb = lds + (cur << 14);
    char* hb = lds + 32768;

    // issue next tile's pix loads (drains at first barrier; ~layer-1 of slack)
    if (tt < 3) {
      char* nb = lds + ((cur ^ 1) << 14);
#pragma unroll
      for (int c = 0; c < 2; ++c) {
        int slot = (w << 7) + (c << 6) + lane;
        int m = slot >> 4, j = slot & 15;
        gl_lds16(pix + (size_t)(pixbase + ((tt + 1) << 6) + m) * IC + ((j ^ (m & 7)) << 3),
                 nb + ((w << 7) + (c << 6)) * 16);
      }
    }

    f32x4 acc[2][4];
    bf16x8 bp[4], bq[4];

    // ================= layer 1: K=128 =================
#pragma unroll
    for (int nf = 0; nf < 2; ++nf)
#pragma unroll
      for (int mf = 0; mf < 4; ++mf) acc[nf][mf] = vzero;

#pragma unroll
    for (int mf = 0; mf < 4; ++mf) {
      int m = (mf << 4) + l15;
      bp[mf] = *reinterpret_cast<const bf16x8*>(pb + (((m << 8) + (kgrp << 1)) ^ ((m & 7) << 4)));
    }
#pragma unroll
    for (int ks = 0; ks < 4; ++ks) {
      if (ks < 3) {
#pragma unroll
        for (int mf = 0; mf < 4; ++mf) {
          int m = (mf << 4) + l15;
          bq[mf] = *reinterpret_cast<const bf16x8*>(
              pb + (((m << 8) + ((ks + 1) << 6) + (kgrp << 1)) ^ ((m & 7) << 4)));
        }
      }
#pragma unroll
      for (int nf = 0; nf < 2; ++nf)
#pragma unroll
        for (int mf = 0; mf < 4; ++mf)
          acc[nf][mf] = __builtin_amdgcn_mfma_f32_16x16x32_bf16(W1r[nf][ks], bp[mf], acc[nf][mf], 0, 0, 0);
#pragma unroll
      for (int mf = 0; mf < 4; ++mf) bp[mf] = bq[mf];
    }

    // epilogue: bias+relu -> h1
#pragma unroll
    for (int nf = 0; nf < 2; ++nf) {
      int n0 = (w << 5) + (nf << 4) + (lg << 2);
      f32x4 bb = *reinterpret_cast<const f32x4*>(b1o + n0);
#pragma unroll
      for (int mf = 0; mf < 4; ++mf) {
        int m = (mf << 4) + l15;
        ushort4 hv;
        hv.x = f2bf(fmaxf(acc[nf][mf][0] + bb[0], 0.f));
        hv.y = f2bf(fmaxf(acc[nf][mf][1] + bb[1], 0.f));
        hv.z = f2bf(fmaxf(acc[nf][mf][2] + bb[2], 0.f));
        hv.w = f2bf(fmaxf(acc[nf][mf][3] + bb[3], 0.f));
        *reinterpret_cast<ushort4*>(hb + (((m << 9) + (n0 << 1)) ^ ((m & 7) << 4))) = hv;
      }
    }
    __syncthreads();   // B1: h1 visible (also drains next-tile pix loads)

    // ================= layer 2: K=256 =================
#pragma unroll
    for (int nf = 0; nf < 2; ++nf)
#pragma unroll
      for (int mf = 0; mf < 4; ++mf) acc[nf][mf] = vzero;

#pragma unroll
    for (int mf = 0; mf < 4; ++mf) {
      int m = (mf << 4) + l15;
      bp[mf] = *reinterpret_cast<const bf16x8*>(hb + (((m << 9) + (kgrp << 1)) ^ ((m & 7) << 4)));
    }
#pragma unroll
    for (int ks = 0; ks < 8; ++ks) {
      if (ks < 7) {
#pragma unroll
        for (int mf = 0; mf < 4; ++mf) {
          int m = (mf << 4) + l15;
          bq[mf] = *reinterpret_cast<const bf16x8*>(
              hb + (((m << 9) + ((ks + 1) << 6) + (kgrp << 1)) ^ ((m & 7) << 4)));
        }
      }
#pragma unroll
      for (int nf = 0; nf < 2; ++nf)
#pragma unroll
        for (int mf = 0; mf < 4; ++mf)
          acc[nf][mf] = __builtin_amdgcn_mfma_f32_16x16x32_bf16(W2r[nf][ks], bp[mf], acc[nf][mf], 0, 0, 0);
#pragma unroll
      for (int mf = 0; mf < 4; ++mf) bp[mf] = bq[mf];
    }
    __syncthreads();   // B2: all h1 reads done

    // epilogue -> h2 (overwrites h1 region)
#pragma unroll
    for (int nf = 0; nf < 2; ++nf) {
      int n0 = (w << 5) + (nf << 4) + (lg << 2);
      f32x4 bb = *reinterpret_cast<const f32x4*>(b2o + n0);
#pragma unroll
      for (int mf = 0; mf < 4; ++mf) {
        int m = (mf << 4) + l15;
        ushort4 hv;
        hv.x = f2bf(fmaxf(acc[nf][mf][0] + bb[0], 0.f));
        hv.y = f2bf(fmaxf(acc[nf][mf][1] + bb[1], 0.f));
        hv.z = f2bf(fmaxf(acc[nf][mf][2] + bb[2], 0.f));
        hv.w = f2bf(fmaxf(acc[nf][mf][3] + bb[3], 0.f));
        *reinterpret_cast<ushort4*>(hb + (((m << 9) + (n0 << 1)) ^ ((m & 7) << 4))) = hv;
      }
    }
    __syncthreads();   // B3: h2 visible

    // ================= layer 3: K-split (wave w: k-half w>>2, px quarter w&3) ==
    f32x4 acc3 = vzero;
    const int m3 = ((w & 3) << 4) + l15;
#pragma unroll
    for (int i = 0; i < 4; ++i) {
      int ks = ((w >> 2) << 2) + i;
      bf16x8 bh = *reinterpret_cast<const bf16x8*>(
          hb + (((m3 << 9) + (ks << 6) + (kgrp << 1)) ^ ((m3 & 7) << 4)));
      acc3 = __builtin_amdgcn_mfma_f32_16x16x32_bf16(W3r[i], bh, acc3, 0, 0, 0);
    }
    // partials -> pix buf[cur] (pix[cur] fully consumed by layer 1)
    if (lane < 16)
      *reinterpret_cast<f32x4*>(pb + (((w << 4) + l15) << 4)) = acc3;
    __syncthreads();   // B4: partials visible

    if (w < 4 && lane < 16) {
      f32x4 s0 = *reinterpret_cast<const f32x4*>(pb + (((w << 4) + l15) << 4));
      f32x4 s1 = *reinterpret_cast<const f32x4*>(pb + ((((w + 4) << 4) + l15) << 4));
      int pixel = pixbase + (tt << 6) + (w << 4) + l15;
      int n = pixel >> 10, p = pixel & 1023;
      int ii = p >> 5, jj = p & 31;
      float* ob = out + ((size_t)((n << 5) + o) << 12) + (ii << 7) + (jj << 1);
      f32x2 r0 = { s0[0] + s1[0] + b3f[(o << 2) + 0], s0[1] + s1[1] + b3f[(o << 2) + 1] };
      f32x2 r1 = { s0[2] + s1[2] + b3f[(o << 2) + 2], s0[3] + s1[3] + b3f[(o << 2) + 3] };
      *reinterpret_cast<f32x2*>(ob) = r0;
      *reinterpret_cast<f32x2*>(ob + 64) = r1;
    }
    __syncthreads();   // B5: partial reads done; next tile may reuse buffers
  }
}

extern "C" void kernel_launch(void* const* d_in, const int* in_sizes, int n_in,
                              void* d_out, int out_size, void* d_ws, size_t ws_size,
                              hipStream_t stream) {
  const float* x  = (const float*)d_in[0];
  const float* W1 = (const float*)d_in[1];
  const float* b1 = (const float*)d_in[2];
  const float* W2 = (const float*)d_in[3];
  const float* b2 = (const float*)d_in[4];
  const float* W3 = (const float*)d_in[5];
  const float* b3 = (const float*)d_in[6];
  float* out = (float*)d_out;

  char* ws = (char*)d_ws;
  unsigned short* pixw = (unsigned short*)(ws);
  unsigned short* W1t  = (unsigned short*)(ws + (size_t)(2u << 20));
  unsigned short* W2t  = (unsigned short*)(ws + (size_t)(4u << 20));
  unsigned short* W3t  = (unsigned short*)(ws + (size_t)(8u << 20));

  // pix[n][p][c] = x[n][c][p]: batch 8, 128x1024 -> 1024x128
  transpose_bf16_k<<<8 * 2 * 16, 256, 0, stream>>>(x, pixw, 128, 1024, 2, 16);
  // W1t[o][n][k] = W1[o][k][n]: batch 32, 128x256 -> 256x128
  transpose_bf16_k<<<32 * 2 * 4, 256, 0, stream>>>(W1, W1t, 128, 256, 2, 4);
  // W2t[o][n][k] = W2[o][k][n]: batch 32, 256x256 -> 256x256
  transpose_bf16_k<<<32 * 4 * 4, 256, 0, stream>>>(W2, W2t, 256, 256, 4, 4);
  conv_w3_k<<<512, 256, 0, stream>>>(W3, W3t);

  fused_mlp_k<<<1024, 512, 0, stream>>>(pixw, W1t, W2t, W3t, b1, b2, b3, out);
}